// Round 9
// baseline (348.149 us; speedup 1.0000x reference)
//
#include <hip/hip_runtime.h>
#include <cstdio>

#define NU 250000
#define NI 250000
#define NE 500000
#define ND 250000            // all three dst domains are 250K
#define NB_SCAN 245          // ceil(ND / 1024)
#define NR 8                 // dst ranges (one per XCD, blockIdx % 8 round-robin)
#define RSZ 31250            // ND / NR
#define HB 1954              // hist blocks = ceil(NE/256)
#define BB 3912              // bucket blocks = ceil(NE/1024)*NR
#define GT 3907              // gemm tiles = ceil(250000/64)

typedef __attribute__((ext_vector_type(8))) short short8v;   // 8 bf16 (4 VGPR)
typedef __attribute__((ext_vector_type(4))) float float4v;   // MFMA acc

// ---- bf16 helpers (bit-level, round-to-nearest-even) ----
__device__ inline unsigned short f2bf(float x) {
  unsigned int b = __float_as_uint(x);
  unsigned int r = (b + 0x7FFFu + ((b >> 16) & 1u)) >> 16;
  return (unsigned short)r;
}
__device__ inline float bf2f(unsigned short u) {
  return __uint_as_float(((unsigned int)u) << 16);
}

__device__ inline void async_copy16(const float* g, float* l) {
  __builtin_amdgcn_global_load_lds((const __attribute__((address_space(1))) void*)g,
                                   (__attribute__((address_space(3))) void*)l, 16, 0, 0);
}

// ---------------- one-tile MFMA GEMM body: 64 nodes, 32 KB LDS, A-frags from L2 table ----------------
// X rows DMA-staged fp32 (source-side XOR pre-swizzle), converted bf16 at read.
// D: col(lane&15) = node, row((lane>>4)*4+r) = outcol -> ushort4 stores.
template <bool TWO>
__device__ inline void gemm_tile(int t, const float* __restrict__ X, int n,
                                 const unsigned short* __restrict__ Ta, const float* __restrict__ ba,
                                 const unsigned short* __restrict__ Tb, const float* __restrict__ bb,
                                 unsigned short* __restrict__ Ya, unsigned short* __restrict__ Yb) {
  __shared__ float sx[64 * 128];             // 32 KB
  const int tid = threadIdx.x;
  const int lane = tid & 63;
  const int wave = tid >> 6;

  // stage tile t: 2048 16B slots, 8 per thread, wave-uniform LDS base + lane*16
  #pragma unroll
  for (int j = 0; j < 8; ++j) {
    int idx = (wave * 8 + j) * 64 + lane;    // 16B slot index
    int row = idx >> 5, u = idx & 31;
    int gr = t * 64 + row; if (gr >= n) gr = n - 1;
    const float* src = X + (size_t)gr * 128 + ((u ^ (row & 7)) << 2);
    float* dst = &sx[(wave * 8 + j) * 256];
    async_copy16(src, dst);
  }
  asm volatile("s_waitcnt vmcnt(0)" ::: "memory");
  __syncthreads();

  const int nl = wave * 16 + (lane & 15);    // node within tile
  const int sw = nl & 7;
  const int cb = (lane >> 4) * 4;

  float4v accA[4] = {};
  float4v accB[4] = {};
  #pragma unroll
  for (int c = 0; c < 4; ++c) {
    short8v a[4], a2[4];
    #pragma unroll
    for (int jm = 0; jm < 4; ++jm) {
      a[jm] = ((const short8v*)Ta)[c * 256 + jm * 64 + lane];
      if constexpr (TWO) a2[jm] = ((const short8v*)Tb)[c * 256 + jm * 64 + lane];
    }
    int s0 = c * 8 + (lane >> 4) * 2;
    float4 f0 = *(const float4*)&sx[nl * 128 + (((s0 + 0) ^ sw) << 2)];
    float4 f1 = *(const float4*)&sx[nl * 128 + (((s0 + 1) ^ sw) << 2)];
    short8v bfr;
    bfr[0] = (short)f2bf(f0.x); bfr[1] = (short)f2bf(f0.y);
    bfr[2] = (short)f2bf(f0.z); bfr[3] = (short)f2bf(f0.w);
    bfr[4] = (short)f2bf(f1.x); bfr[5] = (short)f2bf(f1.y);
    bfr[6] = (short)f2bf(f1.z); bfr[7] = (short)f2bf(f1.w);
    #pragma unroll
    for (int jm = 0; jm < 4; ++jm) {
      accA[jm] = __builtin_amdgcn_mfma_f32_16x16x32_bf16(a[jm], bfr, accA[jm], 0, 0, 0);
      if constexpr (TWO)
        accB[jm] = __builtin_amdgcn_mfma_f32_16x16x32_bf16(a2[jm], bfr, accB[jm], 0, 0, 0);
    }
  }

  int node = t * 64 + nl;
  if (node < n) {
    #pragma unroll
    for (int jm = 0; jm < 4; ++jm) {
      float4 bias = *(const float4*)&ba[jm * 16 + cb];
      ushort4 o;
      o.x = f2bf(accA[jm][0] + bias.x);
      o.y = f2bf(accA[jm][1] + bias.y);
      o.z = f2bf(accA[jm][2] + bias.z);
      o.w = f2bf(accA[jm][3] + bias.w);
      *(ushort4*)&Ya[(size_t)node * 64 + jm * 16 + cb] = o;
      if constexpr (TWO) {
        float4 bias2 = *(const float4*)&bb[jm * 16 + cb];
        ushort4 o2;
        o2.x = f2bf(accB[jm][0] + bias2.x);
        o2.y = f2bf(accB[jm][1] + bias2.y);
        o2.z = f2bf(accB[jm][2] + bias2.z);
        o2.w = f2bf(accB[jm][3] + bias2.w);
        *(ushort4*)&Yb[(size_t)node * 64 + jm * 16 + cb] = o2;
      }
    }
  }
}

// ---------------- fused launch A: hist3 blocks | item-GEMM tiles ----------------
__global__ __launch_bounds__(256) void histF_gemmI_kernel(
    const int* __restrict__ fdst, const int* __restrict__ cdst, const int* __restrict__ rdst,
    int* __restrict__ degf, int* __restrict__ degc, int* __restrict__ degr,
    const float* __restrict__ Xi,
    const unsigned short* __restrict__ Tr, const float* __restrict__ b1r,
    unsigned short* __restrict__ Whr) {
  if (blockIdx.x < HB) {
    int i = blockIdx.x * 256 + threadIdx.x;
    if (i < NE) {
      atomicAdd(&degf[fdst[i]], 1);
      atomicAdd(&degc[cdst[i]], 1);
      atomicAdd(&degr[rdst[i]], 1);
    }
  } else {
    gemm_tile<false>(blockIdx.x - HB, Xi, NI, Tr, b1r, nullptr, nullptr, Whr, nullptr);
  }
}

// ---------------- fused launch B: bucket blocks | user-GEMM tiles ----------------
__global__ __launch_bounds__(256) void bucketF_gemmU_kernel(
    const int* __restrict__ fsrc, const int* __restrict__ fdst,
    const int* __restrict__ csrc, const int* __restrict__ cdst,
    const int* __restrict__ rsrc, const int* __restrict__ rdst,
    int* __restrict__ curf, int* __restrict__ curc, int* __restrict__ curr,
    int* __restrict__ srtf, int* __restrict__ srtc, int* __restrict__ srtr,
    const float* __restrict__ Xu,
    const unsigned short* __restrict__ Tf, const float* __restrict__ b1f,
    const unsigned short* __restrict__ Tc, const float* __restrict__ b1c,
    unsigned short* __restrict__ Whf, unsigned short* __restrict__ Whc) {
  if (blockIdx.x < BB) {
    const int r = blockIdx.x & (NR - 1);
    const int chunk = blockIdx.x >> 3;
    const int lo = r * RSZ, hi = lo + RSZ;
    const int base = chunk * 1024;
    #pragma unroll
    for (int i = 0; i < 4; ++i) {
      int e = base + i * 256 + threadIdx.x;
      if (e < NE) {
        int d0 = fdst[e]; int s0 = fsrc[e];
        if (d0 >= lo && d0 < hi) { int p = atomicAdd(&curf[d0], 1); srtf[p] = s0; }
        int d1 = cdst[e]; int s1 = csrc[e];
        if (d1 >= lo && d1 < hi) { int p = atomicAdd(&curc[d1], 1); srtc[p] = s1; }
        int d2 = rdst[e]; int s2 = rsrc[e];
        if (d2 >= lo && d2 < hi) { int p = atomicAdd(&curr[d2], 1); srtr[p] = s2; }
      }
    }
  } else {
    gemm_tile<true>(blockIdx.x - BB, Xu, NU, Tf, b1f, Tc, b1c, Whf, Whc);
  }
}

// ---------------- scans (unchanged) ----------------
__global__ void scan1_kernel(const int* __restrict__ deg0, const int* __restrict__ deg1,
                             const int* __restrict__ deg2, int* __restrict__ bsum) {
  const int* deg = blockIdx.y == 0 ? deg0 : (blockIdx.y == 1 ? deg1 : deg2);
  int* bs = bsum + blockIdx.y * 256;
  __shared__ int s[256];
  int b = blockIdx.x, t = threadIdx.x;
  int base = b * 1024 + t * 4;
  int v = 0;
  #pragma unroll
  for (int i = 0; i < 4; ++i) if (base + i < ND) v += deg[base + i];
  s[t] = v; __syncthreads();
  for (int off = 128; off > 0; off >>= 1) { if (t < off) s[t] += s[t + off]; __syncthreads(); }
  if (t == 0) bs[b] = s[0];
}

__global__ void scan2_kernel(int* __restrict__ bsum) {
  int* bs = bsum + blockIdx.x * 256;
  __shared__ int s[256];
  int t = threadIdx.x;
  s[t] = (t < NB_SCAN) ? bs[t] : 0;
  __syncthreads();
  for (int off = 1; off < 256; off <<= 1) {
    int x = (t >= off) ? s[t - off] : 0;
    __syncthreads();
    s[t] += x;
    __syncthreads();
  }
  if (t < NB_SCAN) bs[t] = (t == 0) ? 0 : s[t - 1];
}

__global__ void scan3_kernel(const int* __restrict__ deg0, const int* __restrict__ deg1,
                             const int* __restrict__ deg2, const int* __restrict__ bsum,
                             int* __restrict__ offs0, int* __restrict__ offs1, int* __restrict__ offs2,
                             int* __restrict__ cur0, int* __restrict__ cur1, int* __restrict__ cur2) {
  int y = blockIdx.y;
  const int* deg = y == 0 ? deg0 : (y == 1 ? deg1 : deg2);
  int* offs = y == 0 ? offs0 : (y == 1 ? offs1 : offs2);
  int* cursor = y == 0 ? cur0 : (y == 1 ? cur1 : cur2);
  const int* bs = bsum + y * 256;
  __shared__ int s[256];
  int b = blockIdx.x, t = threadIdx.x;
  int base = b * 1024 + t * 4;
  int v[4]; int sum = 0;
  #pragma unroll
  for (int i = 0; i < 4; ++i) { v[i] = (base + i < ND) ? deg[base + i] : 0; sum += v[i]; }
  s[t] = sum; __syncthreads();
  for (int off = 1; off < 256; off <<= 1) {
    int x = (t >= off) ? s[t - off] : 0;
    __syncthreads();
    s[t] += x;
    __syncthreads();
  }
  int run = bs[b] + s[t] - sum;
  #pragma unroll
  for (int i = 0; i < 4; ++i) {
    if (base + i < ND) { offs[base + i] = run; cursor[base + i] = run; run += v[i]; }
  }
  if (b == 0 && t == 0) offs[ND] = NE;
}

// ---------------- W1 fragment table prep ----------------
__global__ void prepw_kernel(const float* __restrict__ W0, const float* __restrict__ W1,
                             const float* __restrict__ W2, unsigned short* __restrict__ T) {
  int gt = blockIdx.x * 256 + threadIdx.x;   // 0..3071
  int et = gt >> 10;
  int g = gt & 1023;
  int gl = g & 63;
  int jm = (g >> 6) & 3;
  int c = g >> 8;
  int kb = c * 32 + (gl >> 4) * 8;
  int col = jm * 16 + (gl & 15);
  const float* W = et == 0 ? W0 : (et == 1 ? W1 : W2);
  short8v u;
  #pragma unroll
  for (int i = 0; i < 8; ++i) u[i] = (short)f2bf(W[(kb + i) * 64 + col]);
  ((short8v*)T)[gt] = u;
}

// ---------------- fused layer-1 aggregation (unchanged from round 8) ----------------
__global__ __launch_bounds__(256) void agg_fused_kernel(
    const unsigned short* __restrict__ Whf, const unsigned short* __restrict__ Whr,
    const unsigned short* __restrict__ Whc,
    const int* __restrict__ offs_f, const int* __restrict__ srt_f,
    const int* __restrict__ offs_r, const int* __restrict__ srt_r,
    const int* __restrict__ offs_c, const int* __restrict__ srt_c,
    const float* __restrict__ W2f, const float* __restrict__ b2f,
    const float* __restrict__ W2c, const float* __restrict__ b2c,
    const float* __restrict__ W2r, const float* __restrict__ b2r,
    float* __restrict__ h2u, float* __restrict__ h2i,
    float* __restrict__ Y2f, float* __restrict__ Y2c, float* __restrict__ Y2r,
    int ub) {
  const int tid = threadIdx.x;
  const int gid = tid >> 4;
  const int q = tid & 15;

  if (blockIdx.x < ub) {
    int d0 = (blockIdx.x * 16 + gid) * 2;
    int d1 = d0 + 1;
    bool v0 = d0 < NU, v1 = d1 < NU;
    int ef0 = v0 ? offs_f[d0] : 0, ef0e = v0 ? offs_f[d0 + 1] : 0;
    int ef1 = v1 ? offs_f[d1] : 0, ef1e = v1 ? offs_f[d1 + 1] : 0;
    int er0 = v0 ? offs_r[d0] : 0, er0e = v0 ? offs_r[d0 + 1] : 0;
    int er1 = v1 ? offs_r[d1] : 0, er1e = v1 ? offs_r[d1 + 1] : 0;
    float rf0 = 1.0f / fmaxf((float)(ef0e - ef0), 1.0f);
    float rf1 = 1.0f / fmaxf((float)(ef1e - ef1), 1.0f);
    float rr0 = 1.0f / fmaxf((float)(er0e - er0), 1.0f);
    float rr1 = 1.0f / fmaxf((float)(er1e - er1), 1.0f);

    float af0[4] = {0, 0, 0, 0}, af1[4] = {0, 0, 0, 0};
    float ar0[4] = {0, 0, 0, 0}, ar1[4] = {0, 0, 0, 0};
    while (ef0 < ef0e || ef1 < ef1e || er0 < er0e || er1 < er1e) {
      bool hf0 = ef0 < ef0e, hf1 = ef1 < ef1e, hr0 = er0 < er0e, hr1 = er1 < er1e;
      ushort4 vf0, vf1, vr0, vr1;
      if (hf0) { int s = srt_f[ef0]; vf0 = *(const ushort4*)&Whf[(size_t)s * 64 + q * 4]; }
      if (hf1) { int s = srt_f[ef1]; vf1 = *(const ushort4*)&Whf[(size_t)s * 64 + q * 4]; }
      if (hr0) { int s = srt_r[er0]; vr0 = *(const ushort4*)&Whr[(size_t)s * 64 + q * 4]; }
      if (hr1) { int s = srt_r[er1]; vr1 = *(const ushort4*)&Whr[(size_t)s * 64 + q * 4]; }
      if (hf0) { af0[0] += bf2f(vf0.x); af0[1] += bf2f(vf0.y); af0[2] += bf2f(vf0.z); af0[3] += bf2f(vf0.w); ++ef0; }
      if (hf1) { af1[0] += bf2f(vf1.x); af1[1] += bf2f(vf1.y); af1[2] += bf2f(vf1.z); af1[3] += bf2f(vf1.w); ++ef1; }
      if (hr0) { ar0[0] += bf2f(vr0.x); ar0[1] += bf2f(vr0.y); ar0[2] += bf2f(vr0.z); ar0[3] += bf2f(vr0.w); ++er0; }
      if (hr1) { ar1[0] += bf2f(vr1.x); ar1[1] += bf2f(vr1.y); ar1[2] += bf2f(vr1.z); ar1[3] += bf2f(vr1.w); ++er1; }
    }

    float h0v[4], h1v[4];
    #pragma unroll
    for (int i = 0; i < 4; ++i) {
      float x0 = af0[i] * rf0 + ar0[i] * rr0;
      h0v[i] = x0 >= 0.f ? x0 : 0.01f * x0;
      float x1 = af1[i] * rf1 + ar1[i] * rr1;
      h1v[i] = x1 >= 0.f ? x1 : 0.01f * x1;
    }
    if (v0) *(float4*)&h2u[(size_t)d0 * 64 + q * 4] = make_float4(h0v[0], h0v[1], h0v[2], h0v[3]);
    if (v1) *(float4*)&h2u[(size_t)d1 * 64 + q * 4] = make_float4(h1v[0], h1v[1], h1v[2], h1v[3]);

    float pf00 = 0, pf01 = 0, pc00 = 0, pc01 = 0;
    float pf10 = 0, pf11 = 0, pc10 = 0, pc11 = 0;
    #pragma unroll
    for (int i = 0; i < 4; ++i) {
      int j = q * 4 + i;
      float wf0 = W2f[j * 2 + 0], wf1 = W2f[j * 2 + 1];
      float wc0 = W2c[j * 2 + 0], wc1 = W2c[j * 2 + 1];
      pf00 += h0v[i] * wf0; pf01 += h0v[i] * wf1;
      pc00 += h0v[i] * wc0; pc01 += h0v[i] * wc1;
      pf10 += h1v[i] * wf0; pf11 += h1v[i] * wf1;
      pc10 += h1v[i] * wc0; pc11 += h1v[i] * wc1;
    }
    #pragma unroll
    for (int off = 1; off < 16; off <<= 1) {
      pf00 += __shfl_xor(pf00, off, 64); pf01 += __shfl_xor(pf01, off, 64);
      pc00 += __shfl_xor(pc00, off, 64); pc01 += __shfl_xor(pc01, off, 64);
      pf10 += __shfl_xor(pf10, off, 64); pf11 += __shfl_xor(pf11, off, 64);
      pc10 += __shfl_xor(pc10, off, 64); pc11 += __shfl_xor(pc11, off, 64);
    }
    if (q == 0) {
      if (v0) {
        Y2f[(size_t)d0 * 2 + 0] = pf00 + b2f[0]; Y2f[(size_t)d0 * 2 + 1] = pf01 + b2f[1];
        Y2c[(size_t)d0 * 2 + 0] = pc00 + b2c[0]; Y2c[(size_t)d0 * 2 + 1] = pc01 + b2c[1];
      }
      if (v1) {
        Y2f[(size_t)d1 * 2 + 0] = pf10 + b2f[0]; Y2f[(size_t)d1 * 2 + 1] = pf11 + b2f[1];
        Y2c[(size_t)d1 * 2 + 0] = pc10 + b2c[0]; Y2c[(size_t)d1 * 2 + 1] = pc11 + b2c[1];
      }
    }
  } else {
    int d0 = ((blockIdx.x - ub) * 16 + gid) * 2;
    int d1 = d0 + 1;
    bool v0 = d0 < NI, v1 = d1 < NI;
    int ec0 = v0 ? offs_c[d0] : 0, ec0e = v0 ? offs_c[d0 + 1] : 0;
    int ec1 = v1 ? offs_c[d1] : 0, ec1e = v1 ? offs_c[d1 + 1] : 0;
    float rc0 = 1.0f / fmaxf((float)(ec0e - ec0), 1.0f);
    float rc1 = 1.0f / fmaxf((float)(ec1e - ec1), 1.0f);

    float ac0[4] = {0, 0, 0, 0}, ac1[4] = {0, 0, 0, 0};
    while (ec0 < ec0e || ec1 < ec1e) {
      bool h0 = ec0 < ec0e, h1 = ec1 < ec1e;
      ushort4 v0v, v1v;
      if (h0) { int s = srt_c[ec0]; v0v = *(const ushort4*)&Whc[(size_t)s * 64 + q * 4]; }
      if (h1) { int s = srt_c[ec1]; v1v = *(const ushort4*)&Whc[(size_t)s * 64 + q * 4]; }
      if (h0) { ac0[0] += bf2f(v0v.x); ac0[1] += bf2f(v0v.y); ac0[2] += bf2f(v0v.z); ac0[3] += bf2f(v0v.w); ++ec0; }
      if (h1) { ac1[0] += bf2f(v1v.x); ac1[1] += bf2f(v1v.y); ac1[2] += bf2f(v1v.z); ac1[3] += bf2f(v1v.w); ++ec1; }
    }

    float h0v[4], h1v[4];
    #pragma unroll
    for (int i = 0; i < 4; ++i) {
      float x0 = ac0[i] * rc0;
      h0v[i] = x0 >= 0.f ? x0 : 0.01f * x0;
      float x1 = ac1[i] * rc1;
      h1v[i] = x1 >= 0.f ? x1 : 0.01f * x1;
    }
    if (v0) *(float4*)&h2i[(size_t)d0 * 64 + q * 4] = make_float4(h0v[0], h0v[1], h0v[2], h0v[3]);
    if (v1) *(float4*)&h2i[(size_t)d1 * 64 + q * 4] = make_float4(h1v[0], h1v[1], h1v[2], h1v[3]);

    float p00 = 0, p01 = 0, p10 = 0, p11 = 0;
    #pragma unroll
    for (int i = 0; i < 4; ++i) {
      int j = q * 4 + i;
      float w0 = W2r[j * 2 + 0], w1 = W2r[j * 2 + 1];
      p00 += h0v[i] * w0; p01 += h0v[i] * w1;
      p10 += h1v[i] * w0; p11 += h1v[i] * w1;
    }
    #pragma unroll
    for (int off = 1; off < 16; off <<= 1) {
      p00 += __shfl_xor(p00, off, 64); p01 += __shfl_xor(p01, off, 64);
      p10 += __shfl_xor(p10, off, 64); p11 += __shfl_xor(p11, off, 64);
    }
    if (q == 0) {
      if (v0) { Y2r[(size_t)d0 * 2 + 0] = p00 + b2r[0]; Y2r[(size_t)d0 * 2 + 1] = p01 + b2r[1]; }
      if (v1) { Y2r[(size_t)d1 * 2 + 0] = p10 + b2r[0]; Y2r[(size_t)d1 * 2 + 1] = p11 + b2r[1]; }
    }
  }
}

// ---------------- fused layer-2 gather (unchanged from round 8) ----------------
__global__ void out_fused_kernel(const float* __restrict__ Y2f, const float* __restrict__ Y2r,
                                 const float* __restrict__ Y2c,
                                 const int* __restrict__ offs_f, const int* __restrict__ srt_f,
                                 const int* __restrict__ offs_r, const int* __restrict__ srt_r,
                                 const int* __restrict__ offs_c, const int* __restrict__ srt_c,
                                 float* __restrict__ out_u, float* __restrict__ out_i, int ub) {
  if (blockIdx.x < ub) {
    int d = blockIdx.x * 256 + threadIdx.x;
    if (d >= NU) return;
    int f = offs_f[d], f1 = offs_f[d + 1];
    int r = offs_r[d], r1 = offs_r[d + 1];
    float rf = 1.0f / fmaxf((float)(f1 - f), 1.0f);
    float rr = 1.0f / fmaxf((float)(r1 - r), 1.0f);
    float a0 = 0.f, a1 = 0.f, c0 = 0.f, c1 = 0.f;
    while (f < f1 || r < r1) {
      bool hf = f < f1, hr = r < r1;
      float2 yf, yr;
      if (hf) { int s = srt_f[f]; yf = *(const float2*)&Y2f[(size_t)s * 2]; }
      if (hr) { int s = srt_r[r]; yr = *(const float2*)&Y2r[(size_t)s * 2]; }
      if (hf) { a0 += yf.x; a1 += yf.y; ++f; }
      if (hr) { c0 += yr.x; c1 += yr.y; ++r; }
    }
    out_u[(size_t)d * 2 + 0] = a0 * rf + c0 * rr;
    out_u[(size_t)d * 2 + 1] = a1 * rf + c1 * rr;
  } else {
    int d = (blockIdx.x - ub) * 256 + threadIdx.x;
    if (d >= NI) return;
    int c = offs_c[d], c1e = offs_c[d + 1];
    float rc = 1.0f / fmaxf((float)(c1e - c), 1.0f);
    float a0 = 0.f, a1 = 0.f;
    for (; c < c1e; ++c) {
      int s = srt_c[c];
      a0 += Y2c[(size_t)s * 2 + 0]; a1 += Y2c[(size_t)s * 2 + 1];
    }
    out_i[(size_t)d * 2 + 0] = a0 * rc;
    out_i[(size_t)d * 2 + 1] = a1 * rc;
  }
}

extern "C" void kernel_launch(void* const* d_in, const int* in_sizes, int n_in,
                              void* d_out, int out_size, void* d_ws, size_t ws_size,
                              hipStream_t stream) {
  const float* feat_user = (const float*)d_in[0];
  const float* feat_item = (const float*)d_in[1];
  const float* W1f = (const float*)d_in[2];  const float* b1f = (const float*)d_in[3];
  const float* W1c = (const float*)d_in[4];  const float* b1c = (const float*)d_in[5];
  const float* W1r = (const float*)d_in[6];  const float* b1r = (const float*)d_in[7];
  const float* W2f = (const float*)d_in[8];  const float* b2f = (const float*)d_in[9];
  const float* W2c = (const float*)d_in[10]; const float* b2c = (const float*)d_in[11];
  const float* W2r = (const float*)d_in[12]; const float* b2r = (const float*)d_in[13];
  const int* fsrc = (const int*)d_in[14];  const int* fdst = (const int*)d_in[15];
  const int* csrc = (const int*)d_in[16];  const int* cdst = (const int*)d_in[17];
  const int* rsrc = (const int*)d_in[18];  const int* rdst = (const int*)d_in[19];

  float* out = (float*)d_out;
  float* out_u = out;                 // [NU*2]
  float* out_i = out + 2 * NU;        // [NI*2]
  float* h2u  = out + 1000000;        // [NU*64]
  float* h2i  = out + 17000000;       // [NI*64]

  // ---- workspace layout ----
  unsigned short* Whf = (unsigned short*)d_ws;        // 16M bf16 = 32 MB each
  unsigned short* Whc = Whf + 16000000;
  unsigned short* Whr = Whc + 16000000;
  unsigned short* Wtab = Whr + 16000000;              // 3*1024 frags * 8 bf16 = 24576 shorts
  unsigned short* Tf = Wtab;
  unsigned short* Tc = Wtab + 8192;
  unsigned short* Tr = Wtab + 16384;
  int* ibase = (int*)(Wtab + 24576);
  const int P = 250304;                               // padded per-array stride (ints)
  int* offs_f = ibase;            int* offs_c = offs_f + P;  int* offs_r = offs_c + P;
  int* cur_f  = offs_r + P;       int* cur_c  = cur_f + P;   int* cur_r  = cur_c + P;
  int* deg_f  = cur_r + P;        int* deg_c  = deg_f + P;   int* deg_r  = deg_c + P;  // contiguous: 1 memset
  int* srt_f  = deg_r + P;
  int* srt_c  = srt_f + 500096;
  int* srt_r  = srt_c + 500096;
  int* bsum   = srt_r + 500096;                       // 768 ints (3 x 256)
  float* Y2f  = (float*)(bsum + 768);
  float* Y2c  = Y2f + 500000;
  float* Y2r  = Y2c + 500000;

  size_t need = 96000000ull + 24576ull * 2ull
              + (9ull * P + 3ull * 500096ull + 768ull + 1500000ull) * 4ull;
  if (ws_size < need) {
    fprintf(stderr, "kernel_launch: ws too small (%zu < %zu)\n", ws_size, need);
    return;
  }

  hipMemsetAsync(deg_f, 0, (size_t)(3 * P) * 4, stream);

  // W1 fragment tables (48 KB, L2-resident for the GEMMs)
  prepw_kernel<<<12, 256, 0, stream>>>(W1f, W1c, W1r, Wtab);

  // launch A: hist3 | item-GEMM (independent work co-scheduled in one launch)
  histF_gemmI_kernel<<<HB + GT, 256, 0, stream>>>(fdst, cdst, rdst, deg_f, deg_c, deg_r,
                                                  feat_item, Tr, b1r, Whr);

  // scans (exclusive prefix over degrees -> offs/cursors)
  scan1_kernel<<<dim3(NB_SCAN, 3), 256, 0, stream>>>(deg_f, deg_c, deg_r, bsum);
  scan2_kernel<<<3, 256, 0, stream>>>(bsum);
  scan3_kernel<<<dim3(NB_SCAN, 3), 256, 0, stream>>>(deg_f, deg_c, deg_r, bsum,
                                                     offs_f, offs_c, offs_r,
                                                     cur_f, cur_c, cur_r);

  // launch B: partitioned bucket fill | user-GEMM (independent, co-scheduled)
  bucketF_gemmU_kernel<<<BB + GT, 256, 0, stream>>>(fsrc, fdst, csrc, cdst, rsrc, rdst,
                                                    cur_f, cur_c, cur_r, srt_f, srt_c, srt_r,
                                                    feat_user, Tf, b1f, Tc, b1c, Whf, Whc);

  // fused layer-1 aggregation (user + item)
  const int ub = (NU + 31) / 32;                      // 7813
  agg_fused_kernel<<<2 * ub, 256, 0, stream>>>(Whf, Whr, Whc,
                                               offs_f, srt_f, offs_r, srt_r, offs_c, srt_c,
                                               W2f, b2f, W2c, b2c, W2r, b2r,
                                               h2u, h2i, Y2f, Y2c, Y2r, ub);

  // fused layer-2 gather
  const int ob = (NU + 255) / 256;                    // 977
  out_fused_kernel<<<2 * ob, 256, 0, stream>>>(Y2f, Y2r, Y2c,
                                               offs_f, srt_f, offs_r, srt_r, offs_c, srt_c,
                                               out_u, out_i, ob);
}

// Round 11
// 324.270 us; speedup vs baseline: 1.0736x; 1.0736x over previous
//
#include <hip/hip_runtime.h>
#include <cstdio>

#define NU 250000
#define NI 250000
#define NE 500000
#define ND 250000            // all three dst domains are 250K
#define NB_SCAN 245          // ceil(ND / 1024)
#define NR 8                 // dst ranges (one per XCD, blockIdx % 8 round-robin)
#define RSZ 31250            // ND / NR

typedef __attribute__((ext_vector_type(8))) short short8v;   // 8 bf16 (4 VGPR)
typedef __attribute__((ext_vector_type(4))) float float4v;   // MFMA acc / native 16B vector

// ---- bf16 helpers (bit-level, round-to-nearest-even) ----
__device__ inline unsigned short f2bf(float x) {
  unsigned int b = __float_as_uint(x);
  unsigned int r = (b + 0x7FFFu + ((b >> 16) & 1u)) >> 16;
  return (unsigned short)r;
}
__device__ inline float bf2f(unsigned short u) {
  return __uint_as_float(((unsigned int)u) << 16);
}

__device__ inline void async_copy16(const float* g, float* l) {
  __builtin_amdgcn_global_load_lds((const __attribute__((address_space(1))) void*)g,
                                   (__attribute__((address_space(3))) void*)l, 16, 0, 0);
}

__device__ inline void nt_store4(float* p, float a, float b, float c, float d) {
  float4v v; v.x = a; v.y = b; v.z = c; v.w = d;
  __builtin_nontemporal_store(v, (float4v*)p);
}

// ---------------- CSR build ----------------
__global__ void hist3_kernel(const int* __restrict__ fdst, const int* __restrict__ cdst,
                             const int* __restrict__ rdst,
                             int* __restrict__ degf, int* __restrict__ degc, int* __restrict__ degr) {
  int i = blockIdx.x * blockDim.x + threadIdx.x;
  if (i < NE) {
    atomicAdd(&degf[fdst[i]], 1);
    atomicAdd(&degc[cdst[i]], 1);
    atomicAdd(&degr[rdst[i]], 1);
  }
}

__global__ void scan1_kernel(const int* __restrict__ deg0, const int* __restrict__ deg1,
                             const int* __restrict__ deg2, int* __restrict__ bsum) {
  const int* deg = blockIdx.y == 0 ? deg0 : (blockIdx.y == 1 ? deg1 : deg2);
  int* bs = bsum + blockIdx.y * 256;
  __shared__ int s[256];
  int b = blockIdx.x, t = threadIdx.x;
  int base = b * 1024 + t * 4;
  int v = 0;
  #pragma unroll
  for (int i = 0; i < 4; ++i) if (base + i < ND) v += deg[base + i];
  s[t] = v; __syncthreads();
  for (int off = 128; off > 0; off >>= 1) { if (t < off) s[t] += s[t + off]; __syncthreads(); }
  if (t == 0) bs[b] = s[0];
}

// scan3 with scan2 inlined: each block re-scans the 245 block sums locally.
__global__ void scan3_kernel(const int* __restrict__ deg0, const int* __restrict__ deg1,
                             const int* __restrict__ deg2, const int* __restrict__ bsum,
                             int* __restrict__ offs0, int* __restrict__ offs1, int* __restrict__ offs2,
                             int* __restrict__ cur0, int* __restrict__ cur1, int* __restrict__ cur2) {
  int y = blockIdx.y;
  const int* deg = y == 0 ? deg0 : (y == 1 ? deg1 : deg2);
  int* offs = y == 0 ? offs0 : (y == 1 ? offs1 : offs2);
  int* cursor = y == 0 ? cur0 : (y == 1 ? cur1 : cur2);
  const int* bs = bsum + y * 256;
  __shared__ int sb[256];
  __shared__ int s[256];
  int b = blockIdx.x, t = threadIdx.x;

  // inline scan2: inclusive scan of block sums
  sb[t] = (t < NB_SCAN) ? bs[t] : 0;
  __syncthreads();
  for (int off = 1; off < 256; off <<= 1) {
    int x = (t >= off) ? sb[t - off] : 0;
    __syncthreads();
    sb[t] += x;
    __syncthreads();
  }
  int blockbase = (b == 0) ? 0 : sb[b - 1];

  int base = b * 1024 + t * 4;
  int v[4]; int sum = 0;
  #pragma unroll
  for (int i = 0; i < 4; ++i) { v[i] = (base + i < ND) ? deg[base + i] : 0; sum += v[i]; }
  s[t] = sum; __syncthreads();
  for (int off = 1; off < 256; off <<= 1) {
    int x = (t >= off) ? s[t - off] : 0;
    __syncthreads();
    s[t] += x;
    __syncthreads();
  }
  int run = blockbase + s[t] - sum;
  #pragma unroll
  for (int i = 0; i < 4; ++i) {
    if (base + i < ND) { offs[base + i] = run; cursor[base + i] = run; run += v[i]; }
  }
  if (b == 0 && t == 0) offs[ND] = NE;
}

// Partitioned bucket fill: range r = blockIdx&7 (one XCD under round-robin dispatch).
__global__ void bucket_part_kernel(const int* __restrict__ fsrc, const int* __restrict__ fdst,
                                   const int* __restrict__ csrc, const int* __restrict__ cdst,
                                   const int* __restrict__ rsrc, const int* __restrict__ rdst,
                                   int* __restrict__ curf, int* __restrict__ curc, int* __restrict__ curr,
                                   int* __restrict__ srtf, int* __restrict__ srtc, int* __restrict__ srtr) {
  const int r = blockIdx.x & (NR - 1);
  const int chunk = blockIdx.x >> 3;
  const int lo = r * RSZ, hi = lo + RSZ;
  const int base = chunk * 1024;
  #pragma unroll
  for (int i = 0; i < 4; ++i) {
    int e = base + i * 256 + threadIdx.x;
    if (e < NE) {
      int d0 = fdst[e]; int s0 = fsrc[e];
      if (d0 >= lo && d0 < hi) { int p = atomicAdd(&curf[d0], 1); srtf[p] = s0; }
      int d1 = cdst[e]; int s1 = csrc[e];
      if (d1 >= lo && d1 < hi) { int p = atomicAdd(&curc[d1], 1); srtc[p] = s1; }
      int d2 = rdst[e]; int s2 = rsrc[e];
      if (d2 >= lo && d2 < hi) { int p = atomicAdd(&curr[d2], 1); srtr[p] = s2; }
    }
  }
}

// ---------------- W1 fragment table prep ----------------
__global__ void prepw_kernel(const float* __restrict__ W0, const float* __restrict__ W1,
                             const float* __restrict__ W2, unsigned short* __restrict__ T) {
  int gt = blockIdx.x * 256 + threadIdx.x;   // 0..3071
  int et = gt >> 10;
  int g = gt & 1023;
  int gl = g & 63;
  int jm = (g >> 6) & 3;
  int c = g >> 8;
  int kb = c * 32 + (gl >> 4) * 8;
  int col = jm * 16 + (gl & 15);
  const float* W = et == 0 ? W0 : (et == 1 ? W1 : W2);
  short8v u;
  #pragma unroll
  for (int i = 0; i < 8; ++i) u[i] = (short)f2bf(W[(kb + i) * 64 + col]);
  ((short8v*)T)[gt] = u;
}

// ---------------- persistent DMA-staged GEMM phase (round-7 body as device fn) ----------------
template <bool TWO>
__device__ inline void gemm_persist(float (*sx)[64 * 128],
                                    const float* __restrict__ X, int n, int ntiles,
                                    const unsigned short* __restrict__ Ta, const float* __restrict__ ba,
                                    const unsigned short* __restrict__ Tb, const float* __restrict__ bb,
                                    unsigned short* __restrict__ Ya, unsigned short* __restrict__ Yb) {
  const int tid = threadIdx.x;
  const int lane = tid & 63;
  const int wave = tid >> 6;
  const int cb = (lane >> 4) * 4;

  short8v A[4][4], B[4][4];
  #pragma unroll
  for (int c = 0; c < 4; ++c) {
    #pragma unroll
    for (int jm = 0; jm < 4; ++jm) {
      A[c][jm] = ((const short8v*)Ta)[c * 256 + jm * 64 + lane];
      if constexpr (TWO) B[c][jm] = ((const short8v*)Tb)[c * 256 + jm * 64 + lane];
    }
  }
  float4 bias_a[4], bias_b[4];
  #pragma unroll
  for (int jm = 0; jm < 4; ++jm) {
    bias_a[jm] = *(const float4*)&ba[jm * 16 + cb];
    if constexpr (TWO) bias_b[jm] = *(const float4*)&bb[jm * 16 + cb];
  }

  const int nl = wave * 16 + (lane & 15);
  const int sw = nl & 7;

  int t = blockIdx.x;
  if (t >= ntiles) return;
  {
    #pragma unroll
    for (int j = 0; j < 8; ++j) {
      int idx = (wave * 8 + j) * 64 + lane;
      int row = idx >> 5, u = idx & 31;
      int gr = t * 64 + row; if (gr >= n) gr = n - 1;
      const float* src = X + (size_t)gr * 128 + ((u ^ (row & 7)) << 2);
      float* dst = &sx[0][(wave * 8 + j) * 256];
      async_copy16(src, dst);
    }
  }
  asm volatile("s_waitcnt vmcnt(0)" ::: "memory");
  __syncthreads();

  int cur = 0;
  while (true) {
    int tn = t + (int)gridDim.x;
    bool more = (tn < ntiles);
    if (more) {
      #pragma unroll
      for (int j = 0; j < 8; ++j) {
        int idx = (wave * 8 + j) * 64 + lane;
        int row = idx >> 5, u = idx & 31;
        int gr = tn * 64 + row; if (gr >= n) gr = n - 1;
        const float* src = X + (size_t)gr * 128 + ((u ^ (row & 7)) << 2);
        float* dst = &sx[cur ^ 1][(wave * 8 + j) * 256];
        async_copy16(src, dst);
      }
    }

    float4v accA[4] = {};
    float4v accB[4] = {};
    #pragma unroll
    for (int c = 0; c < 4; ++c) {
      int s0 = c * 8 + (lane >> 4) * 2;
      float4 f0 = *(const float4*)&sx[cur][nl * 128 + (((s0 + 0) ^ sw) << 2)];
      float4 f1 = *(const float4*)&sx[cur][nl * 128 + (((s0 + 1) ^ sw) << 2)];
      short8v bfr;
      bfr[0] = (short)f2bf(f0.x); bfr[1] = (short)f2bf(f0.y);
      bfr[2] = (short)f2bf(f0.z); bfr[3] = (short)f2bf(f0.w);
      bfr[4] = (short)f2bf(f1.x); bfr[5] = (short)f2bf(f1.y);
      bfr[6] = (short)f2bf(f1.z); bfr[7] = (short)f2bf(f1.w);
      #pragma unroll
      for (int jm = 0; jm < 4; ++jm) {
        accA[jm] = __builtin_amdgcn_mfma_f32_16x16x32_bf16(A[c][jm], bfr, accA[jm], 0, 0, 0);
        if constexpr (TWO)
          accB[jm] = __builtin_amdgcn_mfma_f32_16x16x32_bf16(B[c][jm], bfr, accB[jm], 0, 0, 0);
      }
    }
    int node = t * 64 + nl;
    if (node < n) {
      #pragma unroll
      for (int jm = 0; jm < 4; ++jm) {
        ushort4 o;
        o.x = f2bf(accA[jm][0] + bias_a[jm].x);
        o.y = f2bf(accA[jm][1] + bias_a[jm].y);
        o.z = f2bf(accA[jm][2] + bias_a[jm].z);
        o.w = f2bf(accA[jm][3] + bias_a[jm].w);
        *(ushort4*)&Ya[(size_t)node * 64 + jm * 16 + cb] = o;
        if constexpr (TWO) {
          ushort4 o2;
          o2.x = f2bf(accB[jm][0] + bias_b[jm].x);
          o2.y = f2bf(accB[jm][1] + bias_b[jm].y);
          o2.z = f2bf(accB[jm][2] + bias_b[jm].z);
          o2.w = f2bf(accB[jm][3] + bias_b[jm].w);
          *(ushort4*)&Yb[(size_t)node * 64 + jm * 16 + cb] = o2;
        }
      }
    }

    if (!more) break;
    asm volatile("s_waitcnt vmcnt(0)" ::: "memory");
    __syncthreads();
    cur ^= 1;
    t = tn;
  }
}

// both GEMMs in one persistent launch: user phase then item phase
__global__ __launch_bounds__(256, 2) void gemm_both_kernel(
    const float* __restrict__ Xu, int un, int utiles,
    const float* __restrict__ Xi, int in_, int itiles,
    const unsigned short* __restrict__ Tf, const float* __restrict__ b1f,
    const unsigned short* __restrict__ Tc, const float* __restrict__ b1c,
    const unsigned short* __restrict__ Tr, const float* __restrict__ b1r,
    unsigned short* __restrict__ Whf, unsigned short* __restrict__ Whc,
    unsigned short* __restrict__ Whr) {
  __shared__ float sx[2][64 * 128];
  gemm_persist<true>(sx, Xu, un, utiles, Tf, b1f, Tc, b1c, Whf, Whc);
  __syncthreads();   // phase boundary: all reads of sx done before re-staging
  gemm_persist<false>(sx, Xi, in_, itiles, Tr, b1r, nullptr, nullptr, Whr, nullptr);
}

// ---------------- fused layer-1 aggregation (round-8 body + nontemporal stores) ----------------
__global__ __launch_bounds__(256) void agg_fused_kernel(
    const unsigned short* __restrict__ Whf, const unsigned short* __restrict__ Whr,
    const unsigned short* __restrict__ Whc,
    const int* __restrict__ offs_f, const int* __restrict__ srt_f,
    const int* __restrict__ offs_r, const int* __restrict__ srt_r,
    const int* __restrict__ offs_c, const int* __restrict__ srt_c,
    const float* __restrict__ W2f, const float* __restrict__ b2f,
    const float* __restrict__ W2c, const float* __restrict__ b2c,
    const float* __restrict__ W2r, const float* __restrict__ b2r,
    float* __restrict__ h2u, float* __restrict__ h2i,
    float* __restrict__ Y2f, float* __restrict__ Y2c, float* __restrict__ Y2r,
    int ub) {
  const int tid = threadIdx.x;
  const int gid = tid >> 4;
  const int q = tid & 15;

  if (blockIdx.x < ub) {
    int d0 = (blockIdx.x * 16 + gid) * 2;
    int d1 = d0 + 1;
    bool v0 = d0 < NU, v1 = d1 < NU;
    int ef0 = v0 ? offs_f[d0] : 0, ef0e = v0 ? offs_f[d0 + 1] : 0;
    int ef1 = v1 ? offs_f[d1] : 0, ef1e = v1 ? offs_f[d1 + 1] : 0;
    int er0 = v0 ? offs_r[d0] : 0, er0e = v0 ? offs_r[d0 + 1] : 0;
    int er1 = v1 ? offs_r[d1] : 0, er1e = v1 ? offs_r[d1 + 1] : 0;
    float rf0 = 1.0f / fmaxf((float)(ef0e - ef0), 1.0f);
    float rf1 = 1.0f / fmaxf((float)(ef1e - ef1), 1.0f);
    float rr0 = 1.0f / fmaxf((float)(er0e - er0), 1.0f);
    float rr1 = 1.0f / fmaxf((float)(er1e - er1), 1.0f);

    float af0[4] = {0, 0, 0, 0}, af1[4] = {0, 0, 0, 0};
    float ar0[4] = {0, 0, 0, 0}, ar1[4] = {0, 0, 0, 0};
    while (ef0 < ef0e || ef1 < ef1e || er0 < er0e || er1 < er1e) {
      bool hf0 = ef0 < ef0e, hf1 = ef1 < ef1e, hr0 = er0 < er0e, hr1 = er1 < er1e;
      ushort4 vf0, vf1, vr0, vr1;
      if (hf0) { int s = srt_f[ef0]; vf0 = *(const ushort4*)&Whf[(size_t)s * 64 + q * 4]; }
      if (hf1) { int s = srt_f[ef1]; vf1 = *(const ushort4*)&Whf[(size_t)s * 64 + q * 4]; }
      if (hr0) { int s = srt_r[er0]; vr0 = *(const ushort4*)&Whr[(size_t)s * 64 + q * 4]; }
      if (hr1) { int s = srt_r[er1]; vr1 = *(const ushort4*)&Whr[(size_t)s * 64 + q * 4]; }
      if (hf0) { af0[0] += bf2f(vf0.x); af0[1] += bf2f(vf0.y); af0[2] += bf2f(vf0.z); af0[3] += bf2f(vf0.w); ++ef0; }
      if (hf1) { af1[0] += bf2f(vf1.x); af1[1] += bf2f(vf1.y); af1[2] += bf2f(vf1.z); af1[3] += bf2f(vf1.w); ++ef1; }
      if (hr0) { ar0[0] += bf2f(vr0.x); ar0[1] += bf2f(vr0.y); ar0[2] += bf2f(vr0.z); ar0[3] += bf2f(vr0.w); ++er0; }
      if (hr1) { ar1[0] += bf2f(vr1.x); ar1[1] += bf2f(vr1.y); ar1[2] += bf2f(vr1.z); ar1[3] += bf2f(vr1.w); ++er1; }
    }

    float h0v[4], h1v[4];
    #pragma unroll
    for (int i = 0; i < 4; ++i) {
      float x0 = af0[i] * rf0 + ar0[i] * rr0;
      h0v[i] = x0 >= 0.f ? x0 : 0.01f * x0;
      float x1 = af1[i] * rf1 + ar1[i] * rr1;
      h1v[i] = x1 >= 0.f ? x1 : 0.01f * x1;
    }
    if (v0) nt_store4(&h2u[(size_t)d0 * 64 + q * 4], h0v[0], h0v[1], h0v[2], h0v[3]);
    if (v1) nt_store4(&h2u[(size_t)d1 * 64 + q * 4], h1v[0], h1v[1], h1v[2], h1v[3]);

    float pf00 = 0, pf01 = 0, pc00 = 0, pc01 = 0;
    float pf10 = 0, pf11 = 0, pc10 = 0, pc11 = 0;
    #pragma unroll
    for (int i = 0; i < 4; ++i) {
      int j = q * 4 + i;
      float wf0 = W2f[j * 2 + 0], wf1 = W2f[j * 2 + 1];
      float wc0 = W2c[j * 2 + 0], wc1 = W2c[j * 2 + 1];
      pf00 += h0v[i] * wf0; pf01 += h0v[i] * wf1;
      pc00 += h0v[i] * wc0; pc01 += h0v[i] * wc1;
      pf10 += h1v[i] * wf0; pf11 += h1v[i] * wf1;
      pc10 += h1v[i] * wc0; pc11 += h1v[i] * wc1;
    }
    #pragma unroll
    for (int off = 1; off < 16; off <<= 1) {
      pf00 += __shfl_xor(pf00, off, 64); pf01 += __shfl_xor(pf01, off, 64);
      pc00 += __shfl_xor(pc00, off, 64); pc01 += __shfl_xor(pc01, off, 64);
      pf10 += __shfl_xor(pf10, off, 64); pf11 += __shfl_xor(pf11, off, 64);
      pc10 += __shfl_xor(pc10, off, 64); pc11 += __shfl_xor(pc11, off, 64);
    }
    if (q == 0) {
      if (v0) {
        __builtin_nontemporal_store(pf00 + b2f[0], &Y2f[(size_t)d0 * 2 + 0]);
        __builtin_nontemporal_store(pf01 + b2f[1], &Y2f[(size_t)d0 * 2 + 1]);
        __builtin_nontemporal_store(pc00 + b2c[0], &Y2c[(size_t)d0 * 2 + 0]);
        __builtin_nontemporal_store(pc01 + b2c[1], &Y2c[(size_t)d0 * 2 + 1]);
      }
      if (v1) {
        __builtin_nontemporal_store(pf10 + b2f[0], &Y2f[(size_t)d1 * 2 + 0]);
        __builtin_nontemporal_store(pf11 + b2f[1], &Y2f[(size_t)d1 * 2 + 1]);
        __builtin_nontemporal_store(pc10 + b2c[0], &Y2c[(size_t)d1 * 2 + 0]);
        __builtin_nontemporal_store(pc11 + b2c[1], &Y2c[(size_t)d1 * 2 + 1]);
      }
    }
  } else {
    int d0 = ((blockIdx.x - ub) * 16 + gid) * 2;
    int d1 = d0 + 1;
    bool v0 = d0 < NI, v1 = d1 < NI;
    int ec0 = v0 ? offs_c[d0] : 0, ec0e = v0 ? offs_c[d0 + 1] : 0;
    int ec1 = v1 ? offs_c[d1] : 0, ec1e = v1 ? offs_c[d1 + 1] : 0;
    float rc0 = 1.0f / fmaxf((float)(ec0e - ec0), 1.0f);
    float rc1 = 1.0f / fmaxf((float)(ec1e - ec1), 1.0f);

    float ac0[4] = {0, 0, 0, 0}, ac1[4] = {0, 0, 0, 0};
    while (ec0 < ec0e || ec1 < ec1e) {
      bool h0 = ec0 < ec0e, h1 = ec1 < ec1e;
      ushort4 v0v, v1v;
      if (h0) { int s = srt_c[ec0]; v0v = *(const ushort4*)&Whc[(size_t)s * 64 + q * 4]; }
      if (h1) { int s = srt_c[ec1]; v1v = *(const ushort4*)&Whc[(size_t)s * 64 + q * 4]; }
      if (h0) { ac0[0] += bf2f(v0v.x); ac0[1] += bf2f(v0v.y); ac0[2] += bf2f(v0v.z); ac0[3] += bf2f(v0v.w); ++ec0; }
      if (h1) { ac1[0] += bf2f(v1v.x); ac1[1] += bf2f(v1v.y); ac1[2] += bf2f(v1v.z); ac1[3] += bf2f(v1v.w); ++ec1; }
    }

    float h0v[4], h1v[4];
    #pragma unroll
    for (int i = 0; i < 4; ++i) {
      float x0 = ac0[i] * rc0;
      h0v[i] = x0 >= 0.f ? x0 : 0.01f * x0;
      float x1 = ac1[i] * rc1;
      h1v[i] = x1 >= 0.f ? x1 : 0.01f * x1;
    }
    if (v0) nt_store4(&h2i[(size_t)d0 * 64 + q * 4], h0v[0], h0v[1], h0v[2], h0v[3]);
    if (v1) nt_store4(&h2i[(size_t)d1 * 64 + q * 4], h1v[0], h1v[1], h1v[2], h1v[3]);

    float p00 = 0, p01 = 0, p10 = 0, p11 = 0;
    #pragma unroll
    for (int i = 0; i < 4; ++i) {
      int j = q * 4 + i;
      float w0 = W2r[j * 2 + 0], w1 = W2r[j * 2 + 1];
      p00 += h0v[i] * w0; p01 += h0v[i] * w1;
      p10 += h1v[i] * w0; p11 += h1v[i] * w1;
    }
    #pragma unroll
    for (int off = 1; off < 16; off <<= 1) {
      p00 += __shfl_xor(p00, off, 64); p01 += __shfl_xor(p01, off, 64);
      p10 += __shfl_xor(p10, off, 64); p11 += __shfl_xor(p11, off, 64);
    }
    if (q == 0) {
      if (v0) {
        __builtin_nontemporal_store(p00 + b2r[0], &Y2r[(size_t)d0 * 2 + 0]);
        __builtin_nontemporal_store(p01 + b2r[1], &Y2r[(size_t)d0 * 2 + 1]);
      }
      if (v1) {
        __builtin_nontemporal_store(p10 + b2r[0], &Y2r[(size_t)d1 * 2 + 0]);
        __builtin_nontemporal_store(p11 + b2r[1], &Y2r[(size_t)d1 * 2 + 1]);
      }
    }
  }
}

// ---------------- fused layer-2 gather ----------------
__global__ void out_fused_kernel(const float* __restrict__ Y2f, const float* __restrict__ Y2r,
                                 const float* __restrict__ Y2c,
                                 const int* __restrict__ offs_f, const int* __restrict__ srt_f,
                                 const int* __restrict__ offs_r, const int* __restrict__ srt_r,
                                 const int* __restrict__ offs_c, const int* __restrict__ srt_c,
                                 float* __restrict__ out_u, float* __restrict__ out_i, int ub) {
  if (blockIdx.x < ub) {
    int d = blockIdx.x * 256 + threadIdx.x;
    if (d >= NU) return;
    int f = offs_f[d], f1 = offs_f[d + 1];
    int r = offs_r[d], r1 = offs_r[d + 1];
    float rf = 1.0f / fmaxf((float)(f1 - f), 1.0f);
    float rr = 1.0f / fmaxf((float)(r1 - r), 1.0f);
    float a0 = 0.f, a1 = 0.f, c0 = 0.f, c1 = 0.f;
    while (f < f1 || r < r1) {
      bool hf = f < f1, hr = r < r1;
      float2 yf, yr;
      if (hf) { int s = srt_f[f]; yf = *(const float2*)&Y2f[(size_t)s * 2]; }
      if (hr) { int s = srt_r[r]; yr = *(const float2*)&Y2r[(size_t)s * 2]; }
      if (hf) { a0 += yf.x; a1 += yf.y; ++f; }
      if (hr) { c0 += yr.x; c1 += yr.y; ++r; }
    }
    __builtin_nontemporal_store(a0 * rf + c0 * rr, &out_u[(size_t)d * 2 + 0]);
    __builtin_nontemporal_store(a1 * rf + c1 * rr, &out_u[(size_t)d * 2 + 1]);
  } else {
    int d = (blockIdx.x - ub) * 256 + threadIdx.x;
    if (d >= NI) return;
    int c = offs_c[d], c1e = offs_c[d + 1];
    float rc = 1.0f / fmaxf((float)(c1e - c), 1.0f);
    float a0 = 0.f, a1 = 0.f;
    for (; c < c1e; ++c) {
      int s = srt_c[c];
      a0 += Y2c[(size_t)s * 2 + 0]; a1 += Y2c[(size_t)s * 2 + 1];
    }
    __builtin_nontemporal_store(a0 * rc, &out_i[(size_t)d * 2 + 0]);
    __builtin_nontemporal_store(a1 * rc, &out_i[(size_t)d * 2 + 1]);
  }
}

extern "C" void kernel_launch(void* const* d_in, const int* in_sizes, int n_in,
                              void* d_out, int out_size, void* d_ws, size_t ws_size,
                              hipStream_t stream) {
  const float* feat_user = (const float*)d_in[0];
  const float* feat_item = (const float*)d_in[1];
  const float* W1f = (const float*)d_in[2];  const float* b1f = (const float*)d_in[3];
  const float* W1c = (const float*)d_in[4];  const float* b1c = (const float*)d_in[5];
  const float* W1r = (const float*)d_in[6];  const float* b1r = (const float*)d_in[7];
  const float* W2f = (const float*)d_in[8];  const float* b2f = (const float*)d_in[9];
  const float* W2c = (const float*)d_in[10]; const float* b2c = (const float*)d_in[11];
  const float* W2r = (const float*)d_in[12]; const float* b2r = (const float*)d_in[13];
  const int* fsrc = (const int*)d_in[14];  const int* fdst = (const int*)d_in[15];
  const int* csrc = (const int*)d_in[16];  const int* cdst = (const int*)d_in[17];
  const int* rsrc = (const int*)d_in[18];  const int* rdst = (const int*)d_in[19];

  float* out = (float*)d_out;
  float* out_u = out;                 // [NU*2]
  float* out_i = out + 2 * NU;        // [NI*2]
  float* h2u  = out + 1000000;        // [NU*64]
  float* h2i  = out + 17000000;       // [NI*64]

  // ---- workspace layout ----
  unsigned short* Whf = (unsigned short*)d_ws;        // 16M bf16 = 32 MB each
  unsigned short* Whc = Whf + 16000000;
  unsigned short* Whr = Whc + 16000000;
  unsigned short* Wtab = Whr + 16000000;              // 3*1024 frags * 8 bf16 = 24576 shorts
  unsigned short* Tf = Wtab;
  unsigned short* Tc = Wtab + 8192;
  unsigned short* Tr = Wtab + 16384;
  int* ibase = (int*)(Wtab + 24576);
  const int P = 250304;                               // padded per-array stride (ints)
  int* offs_f = ibase;            int* offs_c = offs_f + P;  int* offs_r = offs_c + P;
  int* cur_f  = offs_r + P;       int* cur_c  = cur_f + P;   int* cur_r  = cur_c + P;
  int* deg_f  = cur_r + P;        int* deg_c  = deg_f + P;   int* deg_r  = deg_c + P;  // contiguous: 1 memset
  int* srt_f  = deg_r + P;
  int* srt_c  = srt_f + 500096;
  int* srt_r  = srt_c + 500096;
  int* bsum   = srt_r + 500096;                       // 768 ints (3 x 256)
  float* Y2f  = (float*)(bsum + 768);
  float* Y2c  = Y2f + 500000;
  float* Y2r  = Y2c + 500000;

  size_t need = 96000000ull + 24576ull * 2ull
              + (9ull * P + 3ull * 500096ull + 768ull + 1500000ull) * 4ull;
  if (ws_size < need) {
    fprintf(stderr, "kernel_launch: ws too small (%zu < %zu)\n", ws_size, need);
    return;
  }

  (void)hipMemsetAsync(deg_f, 0, (size_t)(3 * P) * 4, stream);

  const int eb = (NE + 255) / 256;

  // W1 fragment tables (48 KB, L2-resident for the GEMMs)
  prepw_kernel<<<12, 256, 0, stream>>>(W1f, W1c, W1r, Wtab);

  // both layer-1 GEMMs in one persistent launch (user phase then item phase)
  const int utiles = (NU + 63) / 64;
  const int itiles = (NI + 63) / 64;
  gemm_both_kernel<<<512, 256, 0, stream>>>(feat_user, NU, utiles, feat_item, NI, itiles,
                                            Tf, b1f, Tc, b1c, Tr, b1r, Whf, Whc, Whr);

  // CSR builds (merged counting sort by dst, partitioned bucket fill)
  hist3_kernel<<<eb, 256, 0, stream>>>(fdst, cdst, rdst, deg_f, deg_c, deg_r);
  scan1_kernel<<<dim3(NB_SCAN, 3), 256, 0, stream>>>(deg_f, deg_c, deg_r, bsum);
  scan3_kernel<<<dim3(NB_SCAN, 3), 256, 0, stream>>>(deg_f, deg_c, deg_r, bsum,
                                                     offs_f, offs_c, offs_r,
                                                     cur_f, cur_c, cur_r);
  const int chunks = (NE + 1023) / 1024;              // 489
  bucket_part_kernel<<<chunks * NR, 256, 0, stream>>>(fsrc, fdst, csrc, cdst, rsrc, rdst,
                                                      cur_f, cur_c, cur_r, srt_f, srt_c, srt_r);

  // fused layer-1 aggregation (user + item)
  const int ub = (NU + 31) / 32;                      // 7813
  agg_fused_kernel<<<2 * ub, 256, 0, stream>>>(Whf, Whr, Whc,
                                               offs_f, srt_f, offs_r, srt_r, offs_c, srt_c,
                                               W2f, b2f, W2c, b2c, W2r, b2r,
                                               h2u, h2i, Y2f, Y2c, Y2r, ub);

  // fused layer-2 gather
  const int ob = (NU + 255) / 256;                    // 977
  out_fused_kernel<<<2 * ob, 256, 0, stream>>>(Y2f, Y2r, Y2c,
                                               offs_f, srt_f, offs_r, srt_r, offs_c, srt_c,
                                               out_u, out_i, ob);
}